// Round 3
// baseline (2756.113 us; speedup 1.0000x reference)
//
#include <hip/hip_runtime.h>
#include <stdint.h>

typedef unsigned short u16;
typedef __attribute__((ext_vector_type(8))) short bf16x8;
typedef __attribute__((ext_vector_type(4))) float fx4;

#define MFMA16(a, b, c) __builtin_amdgcn_mfma_f32_16x16x32_bf16((a), (b), (c), 0, 0, 0)

// ---- workspace layout (bytes) ----
// X is dead after enc_kernel finishes; CSAVE overlays X[b=0..1]. Safe: group 0
// writes CSAVE only after consuming all of its X rows.
#define OFF_X      0u            // x bf16 [B][L][256]             67108864
#define OFF_CSAVE  0u            // c fp32 [256][256] (overlays X)
#define OFF_H      67108864u     // H bf16 [577][256][256] rotating 75628544
#define OFF_ENCWT  142737408u    // enc_W^T bf16 [1024][256]         524288
#define OFF_ENCUT  143261696u    // enc_U^T bf16 [1024][256]         524288
#define OFF_CELLT  143785984u    // (cell_W+cell_U)^T bf16           524288
#define OFF_CONVKT 144310272u    // conv k^T bf16 [256][320]         163840
#define OFF_BWT    144474112u    // back_W^T bf16 [64][256]           32768
#define OFF_FWT    144506880u    // fore_W^T bf16 [32][256]           16384
#define OFF_BAR    144523264u    // 16 groups x 4 member-flags (64B/group) 1024
// end: 144524288 bytes

__device__ __forceinline__ u16 f2bf(float f) {
    uint32_t u = __builtin_bit_cast(uint32_t, f);
    u += 0x7FFFu + ((u >> 16) & 1u);   // RNE
    return (u16)(u >> 16);
}
__device__ __forceinline__ float sigm(float x) { return 1.0f / (1.0f + __expf(-x)); }
__device__ __forceinline__ float tanh_f(float x) { return 1.0f - 2.0f / (__expf(2.0f * x) + 1.0f); }

// store 2 bytes bypassing L1/L2 -> lands at device-coherent point (L3)
__device__ __forceinline__ void store_h_sc(const u16* p, uint32_t v) {
    asm volatile("global_store_short %0, %1, off sc0 sc1" :: "v"(p), "v"(v) : "memory");
}
__device__ __forceinline__ void vmcnt0() { asm volatile("s_waitcnt vmcnt(0)" ::: "memory"); }

__device__ __forceinline__ uint32_t aload(const uint32_t* p) {
    return __hip_atomic_load(p, __ATOMIC_RELAXED, __HIP_MEMORY_SCOPE_AGENT);
}
__device__ __forceinline__ void astore(uint32_t* p, uint32_t v) {
    __hip_atomic_store(p, v, __ATOMIC_RELAXED, __HIP_MEMORY_SCOPE_AGENT);
}

// ---------------------------------------------------------------------------
__global__ void zero_kernel(unsigned char* ws) {
    int i = blockIdx.x * blockDim.x + threadIdx.x;   // 16384 threads
    uint32_t* h0 = (uint32_t*)(ws + OFF_H);          // slot 0: 131072 B
    for (int k = i; k < 32768; k += 16384) h0[k] = 0u;
    if (i < 256) ((uint32_t*)(ws + OFF_BAR))[i] = 0u;
}

// ---------------------------------------------------------------------------
__global__ void prep_kernel(const float* enc_W, const float* enc_U, const float* cell_W,
                            const float* cell_U, const float* conv_k, const float* back_W,
                            const float* fore_W, unsigned char* ws) {
    u16* encWt = (u16*)(ws + OFF_ENCWT);
    u16* encUt = (u16*)(ws + OFF_ENCUT);
    u16* cellT = (u16*)(ws + OFF_CELLT);
    u16* convKt = (u16*)(ws + OFF_CONVKT);
    u16* bwt = (u16*)(ws + OFF_BWT);
    u16* fwt = (u16*)(ws + OFF_FWT);
    int idx = blockIdx.x * blockDim.x + threadIdx.x;
    int stride = gridDim.x * blockDim.x;
    for (int i = idx; i < 262144; i += stride) {
        int n = i >> 8, k = i & 255;
        encWt[i] = f2bf(enc_W[k * 1024 + n]);
        encUt[i] = f2bf(enc_U[k * 1024 + n]);
        cellT[i] = f2bf(cell_W[k * 1024 + n] + cell_U[k * 1024 + n]);
    }
    for (int i = idx; i < 81920; i += stride) {
        int u = i / 320, rem = i - u * 320;
        convKt[i] = f2bf(conv_k[rem * 256 + u]);
    }
    for (int i = idx; i < 16384; i += stride) {
        int n = i >> 8, k = i & 255;
        bwt[i] = f2bf(back_W[k * 64 + n]);
    }
    for (int i = idx; i < 8192; i += stride) {
        int n = i >> 8, k = i & 255;
        fwt[i] = f2bf(fore_W[k * 32 + n]);
    }
}

// ---------------------------------------------------------------------------
// Conv1D(same,k=5)+bias+ReLU as MFMA GEMM (unchanged)
__global__ __launch_bounds__(256) void conv_kernel(const float* __restrict__ in,
                                                   const float* __restrict__ conv_b,
                                                   unsigned char* ws) {
    const u16* kt = (const u16*)(ws + OFF_CONVKT);
    u16* xout = (u16*)(ws + OFF_X);
    int w = threadIdx.x >> 6, lane = threadIdx.x & 63;
    int m = lane & 15, q = lane >> 4;
    int mt = blockIdx.x * 4 + w;
    int r0 = mt * 16;
    int b = r0 >> 9;
    int l0 = r0 & 511;

    fx4 acc[16];
#pragma unroll
    for (int nt = 0; nt < 16; ++nt) acc[nt] = (fx4){0.f, 0.f, 0.f, 0.f};

#pragma unroll
    for (int s = 0; s < 10; ++s) {
        int k0 = s * 32 + q * 8;
        int kk = k0 >> 6, c = k0 & 63;
        int l2 = l0 + m + kk - 2;
        bf16x8 af = {0, 0, 0, 0, 0, 0, 0, 0};
        if (l2 >= 0 && l2 < 512) {
            const float* src = in + (((b << 9) + l2) << 6) + c;
            fx4 f0 = *(const fx4*)src;
            fx4 f1 = *(const fx4*)(src + 4);
            af[0] = (short)f2bf(f0[0]); af[1] = (short)f2bf(f0[1]);
            af[2] = (short)f2bf(f0[2]); af[3] = (short)f2bf(f0[3]);
            af[4] = (short)f2bf(f1[0]); af[5] = (short)f2bf(f1[1]);
            af[6] = (short)f2bf(f1[2]); af[7] = (short)f2bf(f1[3]);
        }
#pragma unroll
        for (int nt = 0; nt < 16; ++nt) {
            bf16x8 bf = *(const bf16x8*)(kt + (nt * 16 + m) * 320 + k0);
            acc[nt] = MFMA16(af, bf, acc[nt]);
        }
    }
#pragma unroll
    for (int nt = 0; nt < 16; ++nt) {
        int u = nt * 16 + m;
        float bias = conv_b[u];
#pragma unroll
        for (int r = 0; r < 4; ++r) {
            float v = acc[nt][r] + bias;
            v = v > 0.f ? v : 0.f;
            int row = r0 + q * 4 + r;
            xout[row * 256 + u] = f2bf(v);
        }
    }
}

// ---------------------------------------------------------------------------
// Encoder: 512 steps. 64 WGs = 16 groups (g=bid&15, 16 batch rows) x 4 members
// (p=bid>>4, 64 hidden units each). Sync per step: each WG is sole writer of
// its flag word (flags[g][p] = t+1, sc0sc1 after h-store drain); one poller
// per WG (tid==0) reads the 4 member flags with relaxed agent loads — no
// atomic RMW, minimal L3 contention.
__global__ __launch_bounds__(256, 1) void enc_kernel(const float* __restrict__ enc_b,
                                                     unsigned char* ws) {
    int tid = threadIdx.x;
    int w = tid >> 6, lane = tid & 63, m = lane & 15, q = lane >> 4;
    int bid = blockIdx.x;
    int g = bid & 15, p = bid >> 4;
    int b0 = g * 16;
    int un0 = p * 64 + w * 16;

    const u16* encWt = (const u16*)(ws + OFF_ENCWT);
    const u16* encUt = (const u16*)(ws + OFF_ENCUT);
    const u16* xbf = (const u16*)(ws + OFF_X);
    u16* H = (u16*)(ws + OFF_H);
    float* csave = (float*)(ws + OFF_CSAVE);
    uint32_t* flags = (uint32_t*)(ws + OFF_BAR + g * 64);   // [4] member flags

    bf16x8 wfrag[4][8], ufrag[4][8];
#pragma unroll
    for (int gi = 0; gi < 4; ++gi) {
#pragma unroll
        for (int s = 0; s < 8; ++s) {
            int n = gi * 256 + un0 + m;
            wfrag[gi][s] = *(const bf16x8*)(encWt + n * 256 + s * 32 + q * 8);
            ufrag[gi][s] = *(const bf16x8*)(encUt + n * 256 + s * 32 + q * 8);
        }
    }
    float bi[4], creg[4];
#pragma unroll
    for (int gi = 0; gi < 4; ++gi) bi[gi] = enc_b[gi * 256 + un0 + m];
    creg[0] = creg[1] = creg[2] = creg[3] = 0.f;

    const u16* xrow = xbf + (size_t)(b0 + m) * (512 * 256) + q * 8;

    for (int t = 0; t < 512; ++t) {
        // ---- x part: no peer dependency; overlaps peers' chains ----
        bf16x8 xa[8];
        const u16* xA = xrow + (size_t)t * 256;
#pragma unroll
        for (int s = 0; s < 8; ++s) xa[s] = *(const bf16x8*)(xA + s * 32);
        fx4 acc[4];
#pragma unroll
        for (int gi = 0; gi < 4; ++gi) acc[gi] = (fx4){bi[gi], bi[gi], bi[gi], bi[gi]};
#pragma unroll
        for (int s = 0; s < 8; ++s) {
#pragma unroll
            for (int gi = 0; gi < 4; ++gi)
                acc[gi] = MFMA16(xa[s], wfrag[gi][s], acc[gi]);
        }

        // ---- wait for all 4 members to have published h[t] ----
        if (tid == 0) {
            uint32_t tgt = (uint32_t)t;
            bool ready;
            do {
                uint32_t f0 = aload(flags + 0);
                uint32_t f1 = aload(flags + 1);
                uint32_t f2 = aload(flags + 2);
                uint32_t f3 = aload(flags + 3);
                ready = (f0 >= tgt) & (f1 >= tgt) & (f2 >= tgt) & (f3 >= tgt);
            } while (!ready);
        }
        __syncthreads();

        // ---- h part ----
        const u16* hA = H + (size_t)t * 65536 + (b0 + m) * 256 + q * 8;
        bf16x8 ha[8];
#pragma unroll
        for (int s = 0; s < 8; ++s) ha[s] = *(const bf16x8*)(hA + s * 32);
#pragma unroll
        for (int s = 0; s < 8; ++s) {
#pragma unroll
            for (int gi = 0; gi < 4; ++gi)
                acc[gi] = MFMA16(ha[s], ufrag[gi][s], acc[gi]);
        }

        // ---- gates + h store to slot t+1 (sc0 sc1: straight to L3) ----
        const u16* hw = H + (size_t)(t + 1) * 65536 + un0 + m;
#pragma unroll
        for (int r = 0; r < 4; ++r) {
            float cv = sigm(acc[1][r]) * creg[r] + sigm(acc[0][r]) * tanh_f(acc[2][r]);
            creg[r] = cv;
            float hv = sigm(acc[3][r]) * tanh_f(cv);
            store_h_sc(hw + (b0 + q * 4 + r) * 256, (uint32_t)f2bf(hv));
        }
        vmcnt0();          // h stores at device-coherent point
        __syncthreads();   // all 4 waves drained
        if (tid == 0) {
            vmcnt0();
            astore(flags + p, (uint32_t)(t + 1));   // publish: sole writer
        }
    }

    // hand off c to the decoder (plain stores; kernel-end writeback)
#pragma unroll
    for (int r = 0; r < 4; ++r)
        csave[(b0 + q * 4 + r) * 256 + un0 + m] = creg[r];
}

// ---------------------------------------------------------------------------
// Decoder: 64 steps, input = previous h, combined (cell_W+cell_U).
__global__ __launch_bounds__(256, 1) void dec_kernel(const float* __restrict__ cell_b,
                                                     unsigned char* ws) {
    int tid = threadIdx.x;
    int w = tid >> 6, lane = tid & 63, m = lane & 15, q = lane >> 4;
    int bid = blockIdx.x;
    int g = bid & 15, p = bid >> 4;
    int b0 = g * 16;
    int un0 = p * 64 + w * 16;

    const u16* cellT = (const u16*)(ws + OFF_CELLT);
    u16* H = (u16*)(ws + OFF_H);
    const float* csave = (const float*)(ws + OFF_CSAVE);
    uint32_t* flags = (uint32_t*)(ws + OFF_BAR + g * 64);

    bf16x8 wfrag[4][8];
#pragma unroll
    for (int gi = 0; gi < 4; ++gi) {
#pragma unroll
        for (int s = 0; s < 8; ++s)
            wfrag[gi][s] = *(const bf16x8*)(cellT + (gi * 256 + un0 + m) * 256 + s * 32 + q * 8);
    }
    float bi[4], creg[4];
#pragma unroll
    for (int gi = 0; gi < 4; ++gi) bi[gi] = cell_b[gi * 256 + un0 + m];
#pragma unroll
    for (int r = 0; r < 4; ++r) creg[r] = csave[(b0 + q * 4 + r) * 256 + un0 + m];

    for (int t = 0; t < 64; ++t) {
        if (tid == 0) {
            uint32_t tgt = (uint32_t)(512 + t);   // encoder left flags at 512
            bool ready;
            do {
                uint32_t f0 = aload(flags + 0);
                uint32_t f1 = aload(flags + 1);
                uint32_t f2 = aload(flags + 2);
                uint32_t f3 = aload(flags + 3);
                ready = (f0 >= tgt) & (f1 >= tgt) & (f2 >= tgt) & (f3 >= tgt);
            } while (!ready);
        }
        __syncthreads();

        const u16* hA = H + (size_t)(512 + t) * 65536 + (b0 + m) * 256 + q * 8;
        bf16x8 ha[8];
#pragma unroll
        for (int s = 0; s < 8; ++s) ha[s] = *(const bf16x8*)(hA + s * 32);
        fx4 acc[4];
#pragma unroll
        for (int gi = 0; gi < 4; ++gi) acc[gi] = (fx4){bi[gi], bi[gi], bi[gi], bi[gi]};
#pragma unroll
        for (int s = 0; s < 8; ++s) {
#pragma unroll
            for (int gi = 0; gi < 4; ++gi)
                acc[gi] = MFMA16(ha[s], wfrag[gi][s], acc[gi]);
        }

        const u16* hw = H + (size_t)(513 + t) * 65536 + un0 + m;
#pragma unroll
        for (int r = 0; r < 4; ++r) {
            float cv = sigm(acc[1][r]) * creg[r] + sigm(acc[0][r]) * tanh_f(acc[2][r]);
            creg[r] = cv;
            float hv = sigm(acc[3][r]) * tanh_f(cv);
            store_h_sc(hw + (b0 + q * 4 + r) * 256, (uint32_t)f2bf(hv));
        }
        vmcnt0();
        __syncthreads();
        if (tid == 0) {
            vmcnt0();
            astore(flags + p, (uint32_t)(513 + t));
        }
    }
}

// ---------------------------------------------------------------------------
__global__ __launch_bounds__(256) void out_gemm(const u16* __restrict__ A,
                                                const u16* __restrict__ Bt,
                                                const float* __restrict__ bias,
                                                float* __restrict__ out,
                                                int ncols, int seqlen) {
    int w = threadIdx.x >> 6, lane = threadIdx.x & 63, m = lane & 15, q = lane >> 4;
    int mt = blockIdx.x * 4 + w;
    int s = mt >> 4;
    int b0 = (mt & 15) * 16;
    bf16x8 af[8];
    const u16* Arow = A + ((size_t)s * 256 + b0 + m) * 256 + q * 8;
#pragma unroll
    for (int ss = 0; ss < 8; ++ss) af[ss] = *(const bf16x8*)(Arow + ss * 32);
    int ntiles = ncols >> 4;
    for (int nt = 0; nt < ntiles; ++nt) {
        fx4 acc = (fx4){0.f, 0.f, 0.f, 0.f};
#pragma unroll
        for (int ss = 0; ss < 8; ++ss) {
            bf16x8 bf = *(const bf16x8*)(Bt + (nt * 16 + m) * 256 + ss * 32 + q * 8);
            acc = MFMA16(af[ss], bf, acc);
        }
        int col = nt * 16 + m;
        float bv = bias[col];
#pragma unroll
        for (int r = 0; r < 4; ++r) {
            int b = b0 + q * 4 + r;
            out[((size_t)b * seqlen + s) * ncols + col] = acc[r] + bv;
        }
    }
}

// ---------------------------------------------------------------------------
extern "C" void kernel_launch(void* const* d_in, const int* in_sizes, int n_in,
                              void* d_out, int out_size, void* d_ws, size_t ws_size,
                              hipStream_t stream) {
    const float* inputs = (const float*)d_in[0];
    const float* conv_k = (const float*)d_in[1];
    const float* conv_b = (const float*)d_in[2];
    const float* enc_W  = (const float*)d_in[3];
    const float* enc_U  = (const float*)d_in[4];
    const float* enc_b  = (const float*)d_in[5];
    const float* cell_W = (const float*)d_in[6];
    const float* cell_U = (const float*)d_in[7];
    const float* cell_b = (const float*)d_in[8];
    const float* fore_W = (const float*)d_in[9];
    const float* fore_b = (const float*)d_in[10];
    const float* back_W = (const float*)d_in[11];
    const float* back_b = (const float*)d_in[12];
    unsigned char* ws = (unsigned char*)d_ws;
    float* out = (float*)d_out;

    zero_kernel<<<64, 256, 0, stream>>>(ws);
    prep_kernel<<<1024, 256, 0, stream>>>(enc_W, enc_U, cell_W, cell_U, conv_k, back_W, fore_W, ws);
    conv_kernel<<<2048, 256, 0, stream>>>(inputs, conv_b, ws);
    enc_kernel<<<64, 256, 0, stream>>>(enc_b, ws);
    dec_kernel<<<64, 256, 0, stream>>>(cell_b, ws);

    const u16* H = (const u16*)(ws + OFF_H);
    // backcast: slots 1..512 -> out[b][l][64] at float offset 524288
    out_gemm<<<2048, 256, 0, stream>>>(H + (size_t)1 * 65536, (const u16*)(ws + OFF_BWT),
                                       back_b, out + 524288, 64, 512);
    // forecast: slots 513..576 -> out[b][j][32]
    out_gemm<<<256, 256, 0, stream>>>(H + (size_t)513 * 65536, (const u16*)(ws + OFF_FWT),
                                      fore_b, out, 32, 64);
}